// Round 8
// baseline (284.533 us; speedup 1.0000x reference)
//
#include <hip/hip_runtime.h>

#define IN_DIM 256
#define HID 64
#define HEADS 4
#define C1 256   // HID*HEADS

typedef __attribute__((ext_vector_type(4))) float  f32x4;
typedef __attribute__((ext_vector_type(8))) short  short8;
typedef __attribute__((ext_vector_type(8))) unsigned short ushort8;
typedef __attribute__((ext_vector_type(4))) unsigned short ushort4v;

static __device__ __forceinline__ unsigned short f2bf(float f) {
  union { float f; unsigned int u; } v; v.f = f;
  unsigned int r = v.u + 0x7fffu + ((v.u >> 16) & 1u);   // RNE
  return (unsigned short)(r >> 16);
}
static __device__ __forceinline__ float bf2f(unsigned short u) {
  union { unsigned int u; float f; } v; v.u = ((unsigned int)u) << 16;
  return v.f;
}

// ---------------------------------------------------------------------------
// CSR build
// ---------------------------------------------------------------------------

__global__ __launch_bounds__(256) void zero_int_kernel(int* __restrict__ p, int n) {
  int i = blockIdx.x * 256 + threadIdx.x;
  if (i < n) p[i] = 0;
}

__global__ __launch_bounds__(256) void hist_kernel(const int* __restrict__ ei,
                                                   int E, int N, int* __restrict__ counts) {
  int e = blockIdx.x * 256 + threadIdx.x;
  if (e >= E + N) return;
  int dst = (e < E) ? ei[(size_t)E + e] : (e - E);
  atomicAdd(&counts[dst], 1);
}

// --- hierarchical scan: 1024 elements per block ---

__global__ __launch_bounds__(256) void scan1_kernel(const int* __restrict__ counts,
                                                    int* __restrict__ blocksums, int N) {
  int tid = threadIdx.x;
  int base = blockIdx.x * 1024 + tid * 4;
  int s = 0;
  if (base + 3 < N) {
    int4 v = *(const int4*)&counts[base];
    s = v.x + v.y + v.z + v.w;
  } else {
    for (int i = 0; i < 4; ++i) if (base + i < N) s += counts[base + i];
  }
  __shared__ int red[256];
  red[tid] = s;
  __syncthreads();
  for (int off = 128; off; off >>= 1) {
    if (tid < off) red[tid] += red[tid + off];
    __syncthreads();
  }
  if (tid == 0) blocksums[blockIdx.x] = red[0];
}

__global__ __launch_bounds__(64) void scan2_kernel(const int* __restrict__ blocksums,
                                                   int* __restrict__ blockoff, int B) {
  int lane = threadIdx.x;
  int carry = 0;
  for (int base = 0; base < B; base += 64) {
    int v = (base + lane < B) ? blocksums[base + lane] : 0;
    int incl = v;
    #pragma unroll
    for (int off = 1; off < 64; off <<= 1) {
      int t = __shfl_up(incl, off);
      if (lane >= off) incl += t;
    }
    if (base + lane < B) blockoff[base + lane] = carry + incl - v;
    carry += __shfl(incl, 63);
  }
  if (lane == 0) blockoff[B] = carry;   // grand total
}

__global__ __launch_bounds__(256) void scan3_kernel(const int* __restrict__ counts,
                                                    const int* __restrict__ blockoff,
                                                    int* __restrict__ indptr,
                                                    int* __restrict__ fillpos, int N) {
  int tid = threadIdx.x;
  int base = blockIdx.x * 1024 + tid * 4;
  int c0 = 0, c1 = 0, c2 = 0, c3 = 0;
  if (base + 3 < N) {
    int4 v = *(const int4*)&counts[base];
    c0 = v.x; c1 = v.y; c2 = v.z; c3 = v.w;
  } else {
    if (base + 0 < N) c0 = counts[base + 0];
    if (base + 1 < N) c1 = counts[base + 1];
    if (base + 2 < N) c2 = counts[base + 2];
    if (base + 3 < N) c3 = counts[base + 3];
  }
  int s = c0 + c1 + c2 + c3;
  __shared__ int sc[256];
  sc[tid] = s;
  __syncthreads();
  for (int off = 1; off < 256; off <<= 1) {
    int t = (tid >= off) ? sc[tid - off] : 0;
    __syncthreads();
    sc[tid] += t;
    __syncthreads();
  }
  int p = sc[tid] - s + blockoff[blockIdx.x];
  if (base + 0 < N) { indptr[base + 0] = p; fillpos[base + 0] = p; p += c0; }
  if (base + 1 < N) { indptr[base + 1] = p; fillpos[base + 1] = p; p += c1; }
  if (base + 2 < N) { indptr[base + 2] = p; fillpos[base + 2] = p; p += c2; }
  if (base + 3 < N) { indptr[base + 3] = p; fillpos[base + 3] = p; p += c3; }
  if (blockIdx.x == 0 && tid == 0) indptr[N] = blockoff[gridDim.x];
}

__global__ __launch_bounds__(256) void fill_kernel(const int* __restrict__ ei, int E, int N,
                                                   int* __restrict__ fillpos,
                                                   int* __restrict__ srcs,
                                                   int* __restrict__ edst) {
  int e = blockIdx.x * 256 + threadIdx.x;
  if (e >= E + N) return;
  int src, dst;
  if (e < E) { src = ei[e]; dst = ei[(size_t)E + e]; }
  else       { src = e - E; dst = e - E; }
  int pos = atomicAdd(&fillpos[dst], 1);
  srcs[pos] = src;
  edst[pos] = dst;
}

// ---------------------------------------------------------------------------
// W[k][n] (f32, KxNC) -> Wt[n][k] (bf16, NCxK)
// ---------------------------------------------------------------------------

__global__ __launch_bounds__(256) void convwt_kernel(const float* __restrict__ W,
                                                     unsigned short* __restrict__ Wt,
                                                     int K, int NC) {
  int t = blockIdx.x * 256 + threadIdx.x;
  if (t >= K * NC) return;
  int k = t & (K - 1);      // K is 256 (pow2)
  int n = t >> 8;
  Wt[(size_t)n * K + k] = f2bf(W[(size_t)k * NC + n]);
}

// ---------------------------------------------------------------------------
// bf16 MFMA GEMM, BK=64: C[M,NC](bf16) = A[M,K] @ Bt[NC,K](bf16).
// AF32: A is f32 and converted to bf16 during LDS staging (fuses convx).
// 4 waves, each 32x32 (2x2 frags of 16x16x32); 8 MFMA per barrier pair.
// ---------------------------------------------------------------------------

#define LDT2 72   // padded LDS row stride (elements)

template<bool AF32>
__global__ __launch_bounds__(256) void gemm64_kernel(const void* __restrict__ Av,
                                                     const unsigned short* __restrict__ Bt,
                                                     unsigned short* __restrict__ C,
                                                     int M, int NC, int K) {
  __shared__ unsigned short As[64 * LDT2];
  __shared__ unsigned short Bs[64 * LDT2];
  int bm = blockIdx.x * 64, bn = blockIdx.y * 64;
  int tid = threadIdx.x;
  int wid = tid >> 6, lane = tid & 63;
  int wr = (wid >> 1) * 32, wc = (wid & 1) * 32;
  int l15 = lane & 15, lq = lane >> 4;

  f32x4 acc00 = {0,0,0,0}, acc01 = {0,0,0,0}, acc10 = {0,0,0,0}, acc11 = {0,0,0,0};

  for (int k0 = 0; k0 < K; k0 += 64) {
    // ---- stage A (64 rows x 64 k) ----
    if (AF32) {
      const float* A = (const float*)Av;
      int c = (tid & 15) * 4;
      #pragma unroll
      for (int p = 0; p < 4; ++p) {
        int r = p * 16 + (tid >> 4);
        int row = bm + r;
        float4 v = make_float4(0.f, 0.f, 0.f, 0.f);
        if (row < M) v = *(const float4*)&A[(size_t)row * K + k0 + c];
        ushort4v o; o[0]=f2bf(v.x); o[1]=f2bf(v.y); o[2]=f2bf(v.z); o[3]=f2bf(v.w);
        *(ushort4v*)&As[r * LDT2 + c] = o;
      }
    } else {
      const unsigned short* A = (const unsigned short*)Av;
      int r = tid >> 2, seg = (tid & 3) * 16;
      int row = bm + r;
      ushort8 v0 = {0,0,0,0,0,0,0,0}, v1 = {0,0,0,0,0,0,0,0};
      if (row < M) {
        v0 = *(const ushort8*)&A[(size_t)row * K + k0 + seg];
        v1 = *(const ushort8*)&A[(size_t)row * K + k0 + seg + 8];
      }
      *(ushort8*)&As[r * LDT2 + seg]     = v0;
      *(ushort8*)&As[r * LDT2 + seg + 8] = v1;
    }
    // ---- stage B (64 rows x 64 k), always bf16 ----
    {
      int r = tid >> 2, seg = (tid & 3) * 16;
      ushort8 v0 = *(const ushort8*)&Bt[(size_t)(bn + r) * K + k0 + seg];
      ushort8 v1 = *(const ushort8*)&Bt[(size_t)(bn + r) * K + k0 + seg + 8];
      *(ushort8*)&Bs[r * LDT2 + seg]     = v0;
      *(ushort8*)&Bs[r * LDT2 + seg + 8] = v1;
    }
    __syncthreads();

    #pragma unroll
    for (int ks = 0; ks < 2; ++ks) {
      short8 a0 = *(const short8*)&As[(wr + l15) * LDT2 + ks * 32 + lq * 8];
      short8 a1 = *(const short8*)&As[(wr + 16 + l15) * LDT2 + ks * 32 + lq * 8];
      short8 b0 = *(const short8*)&Bs[(wc + l15) * LDT2 + ks * 32 + lq * 8];
      short8 b1 = *(const short8*)&Bs[(wc + 16 + l15) * LDT2 + ks * 32 + lq * 8];
      acc00 = __builtin_amdgcn_mfma_f32_16x16x32_bf16(a0, b0, acc00, 0, 0, 0);
      acc01 = __builtin_amdgcn_mfma_f32_16x16x32_bf16(a0, b1, acc01, 0, 0, 0);
      acc10 = __builtin_amdgcn_mfma_f32_16x16x32_bf16(a1, b0, acc10, 0, 0, 0);
      acc11 = __builtin_amdgcn_mfma_f32_16x16x32_bf16(a1, b1, acc11, 0, 0, 0);
    }
    __syncthreads();
  }

  // C/D layout: col = lane&15, row = (lane>>4)*4 + reg
  #pragma unroll
  for (int r = 0; r < 4; ++r) {
    int row0 = bm + wr + lq * 4 + r;
    int row1 = row0 + 16;
    int colb = bn + wc + l15;
    if (row0 < M) {
      C[(size_t)row0 * NC + colb]      = f2bf(acc00[r]);
      C[(size_t)row0 * NC + colb + 16] = f2bf(acc01[r]);
    }
    if (row1 < M) {
      C[(size_t)row1 * NC + colb]      = f2bf(acc10[r]);
      C[(size_t)row1 * NC + colb + 16] = f2bf(acc11[r]);
    }
  }
}

// ---------------------------------------------------------------------------
// Attention logit projections (bf16 H)
// ---------------------------------------------------------------------------

__global__ __launch_bounds__(256) void alpha1_kernel(const unsigned short* __restrict__ H1b,
                                                     const float* __restrict__ a_src,
                                                     const float* __restrict__ a_dst,
                                                     float* __restrict__ asrc,
                                                     float* __restrict__ adst, int N) {
  int n = blockIdx.x * 4 + (threadIdx.x >> 6);
  if (n >= N) return;
  int lane = threadIdx.x & 63;
  int h = lane >> 4;
  ushort4v raw = *(const ushort4v*)&H1b[(size_t)n * C1 + lane * 4];
  float4 as = *(const float4*)&a_src[h * HID + (lane & 15) * 4];
  float4 ad = *(const float4*)&a_dst[h * HID + (lane & 15) * 4];
  float h0 = bf2f(raw[0]), h1 = bf2f(raw[1]), h2 = bf2f(raw[2]), h3 = bf2f(raw[3]);
  float vs = h0 * as.x + h1 * as.y + h2 * as.z + h3 * as.w;
  float vd = h0 * ad.x + h1 * ad.y + h2 * ad.z + h3 * ad.w;
  #pragma unroll
  for (int off = 1; off < 16; off <<= 1) {
    vs += __shfl_xor(vs, off);
    vd += __shfl_xor(vd, off);
  }
  if ((lane & 15) == 0) {
    asrc[n * HEADS + h] = vs;
    adst[n * HEADS + h] = vd;
  }
}

__global__ __launch_bounds__(256) void alpha2_kernel(const unsigned short* __restrict__ H2b,
                                                     const float* __restrict__ a_src,
                                                     const float* __restrict__ a_dst,
                                                     float* __restrict__ asrc,
                                                     float* __restrict__ adst, int N) {
  int n = blockIdx.x * 4 + (threadIdx.x >> 6);
  if (n >= N) return;
  int lane = threadIdx.x & 63;
  int j = lane & 31;
  unsigned int raw = *(const unsigned int*)&H2b[(size_t)n * HID + j * 2];
  float h0 = bf2f((unsigned short)(raw & 0xffff));
  float h1 = bf2f((unsigned short)(raw >> 16));
  float vs = h0 * a_src[j * 2] + h1 * a_src[j * 2 + 1];
  float vd = h0 * a_dst[j * 2] + h1 * a_dst[j * 2 + 1];
  #pragma unroll
  for (int off = 1; off < 32; off <<= 1) {
    vs += __shfl_xor(vs, off);
    vd += __shfl_xor(vd, off);
  }
  if (lane == 0) { asrc[n] = vs; adst[n] = vd; }
}

// ---------------------------------------------------------------------------
// Edge softmax weights — streaming, no atomics (denominator summed in agg)
// ---------------------------------------------------------------------------

__global__ __launch_bounds__(256) void edgew1_kernel(const int* __restrict__ srcs,
                                                     const int* __restrict__ edst,
                                                     const float* __restrict__ asrc,
                                                     const float* __restrict__ adst,
                                                     float* __restrict__ w, int Etot) {
  int k = blockIdx.x * 256 + threadIdx.x;
  if (k >= Etot) return;
  int s = srcs[k], d = edst[k];
  float4 as = *(const float4*)&asrc[s * 4];
  float4 ad = *(const float4*)&adst[d * 4];
  float e0 = as.x + ad.x; e0 = (e0 > 0.f) ? e0 : 0.2f * e0;
  float e1 = as.y + ad.y; e1 = (e1 > 0.f) ? e1 : 0.2f * e1;
  float e2 = as.z + ad.z; e2 = (e2 > 0.f) ? e2 : 0.2f * e2;
  float e3 = as.w + ad.w; e3 = (e3 > 0.f) ? e3 : 0.2f * e3;
  *(float4*)&w[k * 4] = make_float4(__expf(e0), __expf(e1), __expf(e2), __expf(e3));
}

__global__ __launch_bounds__(256) void edgew2_kernel(const int* __restrict__ srcs,
                                                     const int* __restrict__ edst,
                                                     const float* __restrict__ asrc,
                                                     const float* __restrict__ adst,
                                                     float* __restrict__ w, int Etot) {
  int k = blockIdx.x * 256 + threadIdx.x;
  if (k >= Etot) return;
  float e = asrc[srcs[k]] + adst[edst[k]];
  e = (e > 0.f) ? e : 0.2f * e;
  w[k] = __expf(e);
}

// ---------------------------------------------------------------------------
// GAT agg layer 1: wave per node, 4 edge slots, 32B/lane features.
// lane = (q = l>>4 edge slot, j = l&15 feat group); feats 16j..16j+15.
// w read coalesced: lanes of one iter cover w[4k..4k+15] (64B).
// ---------------------------------------------------------------------------

__global__ __launch_bounds__(256) void gat1_agg(const unsigned short* __restrict__ H1b,
                                                const float* __restrict__ w,
                                                const int* __restrict__ indptr,
                                                const int* __restrict__ srcs,
                                                const float* __restrict__ b1,
                                                const float* __restrict__ g1,
                                                const float* __restrict__ be1,
                                                const float* __restrict__ mu1,
                                                const float* __restrict__ var1,
                                                unsigned short* __restrict__ X2b, int N) {
  int n = blockIdx.x * 4 + (threadIdx.x >> 6);
  if (n >= N) return;
  int lane = threadIdx.x & 63;
  int q = lane >> 4;
  int j = lane & 15;
  int h = j >> 2;
  int start = indptr[n], end = indptr[n + 1];

  float acc[16];
  #pragma unroll
  for (int i = 0; i < 16; ++i) acc[i] = 0.f;
  float wsum = 0.f;

  for (int k = start + q; k < end; k += 4) {
    int s = srcs[k];
    float wt = w[k * 4 + h];
    const ushort8* p = (const ushort8*)&H1b[(size_t)s * C1 + j * 16];
    ushort8 r0 = p[0], r1 = p[1];
    wsum += wt;
    #pragma unroll
    for (int i = 0; i < 8; ++i) {
      acc[i]     += wt * bf2f(r0[i]);
      acc[8 + i] += wt * bf2f(r1[i]);
    }
  }
  #pragma unroll
  for (int i = 0; i < 16; ++i) {
    acc[i] += __shfl_xor(acc[i], 16);
    acc[i] += __shfl_xor(acc[i], 32);
  }
  wsum += __shfl_xor(wsum, 16);
  wsum += __shfl_xor(wsum, 32);

  if (q == 0) {
    float inv = 1.f / (wsum + 1e-16f);
    int f = j * 16;
    ushort8 o0, o1;
    #pragma unroll
    for (int i = 0; i < 16; ++i) {
      float val = (acc[i] * inv + b1[f + i] - mu1[f + i]) *
                  (g1[f + i] * rsqrtf(var1[f + i] + 1e-5f)) + be1[f + i];
      val = (val > 0.f) ? val : (__expf(val) - 1.f);
      if (i < 8) o0[i] = f2bf(val); else o1[i - 8] = f2bf(val);
    }
    *(ushort8*)&X2b[(size_t)n * C1 + f]     = o0;
    *(ushort8*)&X2b[(size_t)n * C1 + f + 8] = o1;
  }
}

// ---------------------------------------------------------------------------
// GAT agg layer 2: wave per node, 8 edge slots, 16B/lane features.
// ---------------------------------------------------------------------------

__global__ __launch_bounds__(256) void gat2_agg(const unsigned short* __restrict__ H2b,
                                                const float* __restrict__ w,
                                                const int* __restrict__ indptr,
                                                const int* __restrict__ srcs,
                                                const float* __restrict__ b2,
                                                const float* __restrict__ g2,
                                                const float* __restrict__ be2,
                                                const float* __restrict__ mu2,
                                                const float* __restrict__ var2,
                                                float* __restrict__ out, int N) {
  int n = blockIdx.x * 4 + (threadIdx.x >> 6);
  if (n >= N) return;
  int lane = threadIdx.x & 63;
  int q = lane >> 3;
  int j = lane & 7;
  int start = indptr[n], end = indptr[n + 1];

  float acc[8];
  #pragma unroll
  for (int i = 0; i < 8; ++i) acc[i] = 0.f;
  float wsum = 0.f;

  for (int k = start + q; k < end; k += 8) {
    int s = srcs[k];
    float wt = w[k];
    ushort8 raw = *(const ushort8*)&H2b[(size_t)s * HID + j * 8];
    wsum += wt;
    #pragma unroll
    for (int i = 0; i < 8; ++i) acc[i] += wt * bf2f(raw[i]);
  }
  #pragma unroll
  for (int i = 0; i < 8; ++i) {
    acc[i] += __shfl_xor(acc[i], 8);
    acc[i] += __shfl_xor(acc[i], 16);
    acc[i] += __shfl_xor(acc[i], 32);
  }
  wsum += __shfl_xor(wsum, 8);
  wsum += __shfl_xor(wsum, 16);
  wsum += __shfl_xor(wsum, 32);

  if (q == 0) {
    float inv = 1.f / (wsum + 1e-16f);
    int f = j * 8;
    float o[8];
    #pragma unroll
    for (int i = 0; i < 8; ++i) {
      float val = (acc[i] * inv + b2[f + i] - mu2[f + i]) *
                  (g2[f + i] * rsqrtf(var2[f + i] + 1e-5f)) + be2[f + i];
      o[i] = (val > 0.f) ? val : (__expf(val) - 1.f);
    }
    *(float4*)&out[(size_t)n * HID + f]     = make_float4(o[0], o[1], o[2], o[3]);
    *(float4*)&out[(size_t)n * HID + f + 4] = make_float4(o[4], o[5], o[6], o[7]);
  }
}

// ---------------------------------------------------------------------------

extern "C" void kernel_launch(void* const* d_in, const int* in_sizes, int n_in,
                              void* d_out, int out_size, void* d_ws, size_t ws_size,
                              hipStream_t stream) {
  const float* x      = (const float*)d_in[0];
  const int*   ei     = (const int*)d_in[1];
  const float* W1     = (const float*)d_in[2];
  const float* a_src1 = (const float*)d_in[3];
  const float* a_dst1 = (const float*)d_in[4];
  const float* b1     = (const float*)d_in[5];
  const float* g1     = (const float*)d_in[6];
  const float* be1    = (const float*)d_in[7];
  const float* mu1    = (const float*)d_in[8];
  const float* var1   = (const float*)d_in[9];
  const float* W2     = (const float*)d_in[10];
  const float* a_src2 = (const float*)d_in[11];
  const float* a_dst2 = (const float*)d_in[12];
  const float* b2     = (const float*)d_in[13];
  const float* g2     = (const float*)d_in[14];
  const float* be2    = (const float*)d_in[15];
  const float* mu2    = (const float*)d_in[16];
  const float* var2   = (const float*)d_in[17];
  float* out = (float*)d_out;

  int N = in_sizes[0] / IN_DIM;
  int E = in_sizes[1] / 2;
  int Etot = E + N;
  int NB = (N + 1023) / 1024;   // scan blocks

  // Workspace (~75 MB):
  //   H1b[N*256]b (reused H2b) | X2b[N*256]b | W1t[256*256]b | W2t[64*256]b |
  //   w1[4*Etot]f (reused w2) | asrc1[4N]f | adst1[4N]f | asrc2[N]f |
  //   adst2[N]f | counts[N] | indptr[N+1] | fillpos[N] | blocksums[NB] |
  //   blockoff[NB+1] | srcs[Etot] | edst[Etot]
  unsigned short* H1b = (unsigned short*)d_ws;
  unsigned short* X2b = H1b + (size_t)N * C1;
  unsigned short* W1t = X2b + (size_t)N * C1;
  unsigned short* W2t = W1t + 256 * 256;
  float* w1    = (float*)(W2t + 64 * 256);
  float* asrc1 = w1 + (size_t)4 * Etot;
  float* adst1 = asrc1 + (size_t)N * HEADS;
  float* asrc2 = adst1 + (size_t)N * HEADS;
  float* adst2 = asrc2 + N;
  int* counts    = (int*)(adst2 + N);
  int* indptr    = counts + N;
  int* fillpos   = indptr + (N + 1);
  int* blocksums = fillpos + N;
  int* blockoff  = blocksums + NB;
  int* srcs      = blockoff + (NB + 1);
  int* edst      = srcs + Etot;
  unsigned short* H2b = H1b;   // H1b dead after gat1_agg
  float* w2 = w1;              // w1 dead before edgew2

  // --- CSR build (hierarchical scan) ---
  zero_int_kernel<<<(N + 255) / 256, 256, 0, stream>>>(counts, N);
  hist_kernel<<<(Etot + 255) / 256, 256, 0, stream>>>(ei, E, N, counts);
  scan1_kernel<<<NB, 256, 0, stream>>>(counts, blocksums, N);
  scan2_kernel<<<1, 64, 0, stream>>>(blocksums, blockoff, NB);
  scan3_kernel<<<NB, 256, 0, stream>>>(counts, blockoff, indptr, fillpos, N);
  fill_kernel<<<(Etot + 255) / 256, 256, 0, stream>>>(ei, E, N, fillpos, srcs, edst);

  // --- Weight transposes ---
  convwt_kernel<<<(256 * 256 + 255) / 256, 256, 0, stream>>>(W1, W1t, 256, C1);
  convwt_kernel<<<(256 * 64 + 255) / 256, 256, 0, stream>>>(W2, W2t, 256, HID);

  // --- Layer 1 (A = x f32, converted in staging) ---
  gemm64_kernel<true><<<dim3((N + 63) / 64, C1 / 64), 256, 0, stream>>>(x, W1t, H1b, N, C1, IN_DIM);
  alpha1_kernel<<<(N + 3) / 4, 256, 0, stream>>>(H1b, a_src1, a_dst1, asrc1, adst1, N);
  edgew1_kernel<<<(Etot + 255) / 256, 256, 0, stream>>>(srcs, edst, asrc1, adst1, w1, Etot);
  gat1_agg<<<(N + 3) / 4, 256, 0, stream>>>(H1b, w1, indptr, srcs,
                                            b1, g1, be1, mu1, var1, X2b, N);

  // --- Layer 2 (A = X2b bf16) ---
  gemm64_kernel<false><<<dim3((N + 63) / 64, HID / 64), 256, 0, stream>>>(X2b, W2t, H2b, N, HID, C1);
  alpha2_kernel<<<(N + 3) / 4, 256, 0, stream>>>(H2b, a_src2, a_dst2, asrc2, adst2, N);
  edgew2_kernel<<<(Etot + 255) / 256, 256, 0, stream>>>(srcs, edst, asrc2, adst2, w2, Etot);
  gat2_agg<<<(N + 3) / 4, 256, 0, stream>>>(H2b, w2, indptr, srcs,
                                            b2, g2, be2, mu2, var2, out, N);
}